// Round 9
// baseline (179.579 us; speedup 1.0000x reference)
//
#include <hip/hip_runtime.h>
#include <hip/hip_bf16.h>

// Problem constants (match reference)
#define NNODE_DIN 128
#define NNODE_DOUT 128
#define DEG 48
#define TOPK 32

typedef _Float16 halfx8 __attribute__((ext_vector_type(8)));
typedef unsigned short ushortx8 __attribute__((ext_vector_type(8)));
typedef float floatx4 __attribute__((ext_vector_type(4)));

__device__ inline unsigned short f2h(float f) {
    _Float16 h = (_Float16)f;
    return __builtin_bit_cast(unsigned short, h);
}
__device__ inline float h2f(unsigned short u) {
    return (float)__builtin_bit_cast(_Float16, u);
}
// Raw transcendentals: proven correct in rounds 1-8 (absmax unchanged).
__device__ inline float fast_sqrt(float x) {
    float r; asm("v_sqrt_f32 %0, %1" : "=v"(r) : "v"(x)); return r;
}
__device__ inline float fast_exp(float x) {  // e^x, x <= 0 here (no overflow path)
    float t = x * 1.44269504088896341f;
    float r; asm("v_exp_f32 %0, %1" : "=v"(r) : "v"(t)); return r;
}
__device__ inline float fast_rcp(float x) {
    float r; asm("v_rcp_f32 %0, %1" : "=v"(r) : "v"(x)); return r;
}

// ---------------------------------------------------------------------------
// Kernel 0: pre-swizzle W^T into split-FP16 MFMA B-fragments (unchanged).
// ---------------------------------------------------------------------------
__global__ __launch_bounds__(256) void k0_wprep(
    const float* __restrict__ w, unsigned short* __restrict__ wth,
    unsigned short* __restrict__ wtl) {
    int tid = blockIdx.x * 256 + threadIdx.x;  // 0..2047
    int lane = tid & 63;
    int kt = (tid >> 6) & 3;
    int nt = tid >> 8;
    int m = lane & 15, q = lane >> 4;
    int nn = nt * 16 + m;
    int k0 = kt * 32 + q * 8;
    ushortx8 uh, ul;
#pragma unroll
    for (int e = 0; e < 8; ++e) {
        float v = w[(size_t)(k0 + e) * 128 + nn];
        unsigned short h = f2h(v);
        uh[e] = h;
        ul[e] = f2h(v - h2f(h));
    }
    *(ushortx8*)(wth + tid * 8) = uh;
    *(ushortx8*)(wtl + tid * 8) = ul;
}

// ---------------------------------------------------------------------------
// Kernel 1: x = feat @ W via split-FP16 MFMA. Round-6 shape (best measured
// residue 83.6us; round-7 4-wave split regressed it). FROZEN.
// ---------------------------------------------------------------------------
__global__ __launch_bounds__(64, 4) void k1_mfma(
    const float* __restrict__ feat, const unsigned short* __restrict__ wth,
    const unsigned short* __restrict__ wtl, unsigned short* __restrict__ xf,
    int n) {
    __shared__ float s_x[16 * 132];
    int l = threadIdx.x;
    int m = l & 15, q = l >> 4;
    int r0 = blockIdx.x * 16;

    halfx8 ah[4], al[4];
#pragma unroll
    for (int kt = 0; kt < 4; ++kt) {
        float vv[8];
        if (r0 + m < n) {
            const float* src = feat + (size_t)(r0 + m) * 128 + kt * 32 + q * 8;
            float4 v0 = *(const float4*)src;
            float4 v1 = *(const float4*)(src + 4);
            vv[0] = v0.x; vv[1] = v0.y; vv[2] = v0.z; vv[3] = v0.w;
            vv[4] = v1.x; vv[5] = v1.y; vv[6] = v1.z; vv[7] = v1.w;
        } else {
#pragma unroll
            for (int e = 0; e < 8; ++e) vv[e] = 0.0f;
        }
        ushortx8 uh, ul;
#pragma unroll
        for (int e = 0; e < 8; ++e) {
            unsigned short h = f2h(vv[e]);
            uh[e] = h;
            ul[e] = f2h(vv[e] - h2f(h));
        }
        ah[kt] = __builtin_bit_cast(halfx8, uh);
        al[kt] = __builtin_bit_cast(halfx8, ul);
    }

#pragma unroll 2
    for (int nt = 0; nt < 8; ++nt) {
        floatx4 a = (floatx4){0.f, 0.f, 0.f, 0.f};
#pragma unroll
        for (int kt = 0; kt < 4; ++kt) {
            int fo = ((nt * 4 + kt) * 64 + l) * 8;
            halfx8 bh = *(const halfx8*)(wth + fo);
            halfx8 bl = *(const halfx8*)(wtl + fo);
            a = __builtin_amdgcn_mfma_f32_16x16x32_f16(ah[kt], bh, a, 0, 0, 0);
            a = __builtin_amdgcn_mfma_f32_16x16x32_f16(ah[kt], bl, a, 0, 0, 0);
            a = __builtin_amdgcn_mfma_f32_16x16x32_f16(al[kt], bh, a, 0, 0, 0);
        }
#pragma unroll
        for (int r = 0; r < 4; ++r)
            s_x[(q * 4 + r) * 132 + nt * 16 + m] = a[r];
    }
    __syncthreads();

#pragma unroll
    for (int rr = 0; rr < 2; ++rr) {
        int row = rr * 8 + (l >> 3);
        int c0 = (l & 7) * 16;
        if (r0 + row < n) {
            float vv[16];
#pragma unroll
            for (int j = 0; j < 4; ++j) {
                float4 v = *(const float4*)&s_x[row * 132 + c0 + j * 4];
                vv[j * 4 + 0] = v.x; vv[j * 4 + 1] = v.y;
                vv[j * 4 + 2] = v.z; vv[j * 4 + 3] = v.w;
            }
            unsigned u[8];
#pragma unroll
            for (int p = 0; p < 8; ++p) {
                u[p] = (unsigned)f2h(vv[2 * p]) | ((unsigned)f2h(vv[2 * p + 1]) << 16);
            }
            size_t off = (size_t)(r0 + row) * 128 + c0;
            *(uint4*)(xf + off) = make_uint4(u[0], u[1], u[2], u[3]);
            *(uint4*)(xf + off + 8) = make_uint4(u[4], u[5], u[6], u[7]);
        }
    }
}

// ---------------------------------------------------------------------------
// Kernel 2: round-8 2-wave-per-node structure with ONE change: COALESCED-QUAD
// GATHER. Round-8 showed occupancy 40->79% changed nothing -> k2 is bound by
// the divergent-gather service rate (~2.2 cyc per 16B segment). Old mapping
// (m=l&15,q=l>>4) put the 4 lanes sharing one 64B row-chunk in 4 DIFFERENT
// SIMD16 groups -> no intra-group coalescing, 16 line-requests per group.
// New mapping: lane l fetches row s_id[a0+(l>>2)], 16B slice (l&3)*8 -> 4
// adjacent lanes cover one 64B line; 4 lines per SIMD16 group (the minimum).
// Rows land in s_rows (stride 136: store start bank 4(m+q)%32, the exact
// pattern that measured 0 conflicts in r7); MFMA A-frags are then read from
// LDS in MFMA layout. Everything else identical to round 8.
// ---------------------------------------------------------------------------
__global__ __launch_bounds__(128, 4) void k2_conv(
    const float* __restrict__ ew, const int* __restrict__ nbr,
    const float* __restrict__ bias, const unsigned short* __restrict__ xf,
    float* __restrict__ outp, int n) {
    __shared__ float s_w[52];
    __shared__ int s_nb[52];
    __shared__ float s_tw[32];
    __shared__ int s_id[32];
    __shared__ float s_diag[32];
    __shared__ float s_dist[32];
    __shared__ float s_omega[32];
    __shared__ _Float16 s_rows[32][136];  // 8.7 KB, padded stride (r7-proven)

    int i = blockIdx.x;
    int t = threadIdx.x;
    int w = t >> 6;   // wave 0..1
    int l = t & 63;

    // A: candidates = 48 neighbors + self loop (threads 0..48)
    if (t < DEG + 1) {
        bool self = (t == DEG);
        s_w[t] = self ? 1.0f : ew[(size_t)i * DEG + t];
        s_nb[t] = self ? i : nbr[(size_t)i * DEG + t];
    }
    __syncthreads();

    // B: rank-based top-k (exact jax.lax.top_k tie semantics); rank == slot
    if (t < DEG + 1) {
        float wj = s_w[t];
        int rank = 0;
#pragma unroll
        for (int t2 = 0; t2 < DEG + 1; ++t2) {
            float wt = s_w[t2];
            rank += (wt > wj) || ((wt == wj) && (t2 < t)) ? 1 : 0;
        }
        if (rank < TOPK) {
            s_tw[rank] = wj;
            s_id[rank] = s_nb[t];
        }
    }
    __syncthreads();

    // C: COALESCED gather. Wave w owns rows [16w,16w+16). Lane l fetches
    // row s_id[a0 + (l>>2)], 16B slice (l&3): quads of adjacent lanes read
    // consecutive 16B chunks of one row -> 64B-line coalescing per quad.
    int a0 = w * 16;
    int o0 = 16 - a0;
    {
        int m2 = l >> 2;        // row within own 16
        int q2 = l & 3;         // 16B slice within 64B chunk
        int rowg = s_id[a0 + m2];
        const _Float16* gp = (const _Float16*)xf + (size_t)rowg * 128 + q2 * 8;
#pragma unroll
        for (int kt = 0; kt < 4; ++kt) {
            halfx8 v = *(const halfx8*)(gp + kt * 32);
            *(halfx8*)&s_rows[a0 + m2][kt * 32 + q2 * 8] = v;
        }
    }
    __syncthreads();

    // D: read A/B frags from LDS in MFMA layout, compute Gram quadrants.
    int m = l & 15;
    int q = l >> 4;
    halfx8 Hown[4], Hoth[4];
#pragma unroll
    for (int kt = 0; kt < 4; ++kt) {
        Hown[kt] = *(const halfx8*)&s_rows[a0 + m][kt * 32 + q * 8];
        Hoth[kt] = *(const halfx8*)&s_rows[o0 + m][kt * 32 + q * 8];
    }

    floatx4 accO = (floatx4){0.f, 0.f, 0.f, 0.f};  // G[a0+i][a0+j]
    floatx4 accX = (floatx4){0.f, 0.f, 0.f, 0.f};  // G[a0+i][o0+j]
#pragma unroll
    for (int kt = 0; kt < 4; ++kt) {
        accO = __builtin_amdgcn_mfma_f32_16x16x32_f16(Hown[kt], Hown[kt], accO, 0, 0, 0);
        accX = __builtin_amdgcn_mfma_f32_16x16x32_f16(Hown[kt], Hoth[kt], accX, 0, 0, 0);
    }

    // D2: diagonal from own quadrant (row==col -> d2_aa == 0 exactly)
    if (q == (m >> 2)) {
        s_diag[a0 + m] = accO[m & 3];
    }
    __syncthreads();

    // E: dist[a] = sum over all 32 b of tw[b]*sqrt(d2>0 ? d2 : 0), a in own 16
    {
        float dbO = s_diag[a0 + m];
        float dbX = s_diag[o0 + m];
        float twO = s_tw[a0 + m];
        float twX = s_tw[o0 + m];
#pragma unroll
        for (int r = 0; r < 4; ++r) {
            int a = a0 + q * 4 + r;
            float da = s_diag[a];
            float d2o = da + dbO - 2.0f * accO[r];
            float d2x = da + dbX - 2.0f * accX[r];
            float t0 = (d2o > 0.0f) ? fast_sqrt(d2o) : 0.0f;
            float t1 = (d2x > 0.0f) ? fast_sqrt(d2x) : 0.0f;
            float v = twO * t0 + twX * t1;
            v += __shfl_xor(v, 1);
            v += __shfl_xor(v, 2);
            v += __shfl_xor(v, 4);
            v += __shfl_xor(v, 8);
            if (m == 0) s_dist[a] = v;
        }
    }
    __syncthreads();

    // F: omega = exp(-dist - max(-dist)) * tw, normalized (wave 0 computes)
    if (w == 0) {
        int k32 = l & 31;
        float s = s_dist[k32];
        float mn = s;
        mn = fminf(mn, __shfl_xor(mn, 1));
        mn = fminf(mn, __shfl_xor(mn, 2));
        mn = fminf(mn, __shfl_xor(mn, 4));
        mn = fminf(mn, __shfl_xor(mn, 8));
        mn = fminf(mn, __shfl_xor(mn, 16));
        float e = fast_exp(mn - s) * s_tw[k32];
        float sum = e;
        sum += __shfl_xor(sum, 1);
        sum += __shfl_xor(sum, 2);
        sum += __shfl_xor(sum, 4);
        sum += __shfl_xor(sum, 8);
        sum += __shfl_xor(sum, 16);
        float om = e * fast_rcp(sum);
        if (l < 32) s_omega[l] = om;
    }
    __syncthreads();

    // G: thread t owns output column t; read s_rows[b][t] (2 lanes/bank =
    // free) with broadcast s_omega[b]. One coalesced float store per thread.
    {
        float o = bias[t];
#pragma unroll
        for (int b = 0; b < 32; ++b) {
            o += s_omega[b] * (float)s_rows[b][t];
        }
        outp[(size_t)i * 128 + t] = o;
    }
}

extern "C" void kernel_launch(void* const* d_in, const int* in_sizes, int n_in,
                              void* d_out, int out_size, void* d_ws, size_t ws_size,
                              hipStream_t stream) {
    const float* feat = (const float*)d_in[0];
    const float* ew = (const float*)d_in[1];
    const float* weight = (const float*)d_in[2];
    const float* bias = (const float*)d_in[3];
    const int* nbr = (const int*)d_in[4];
    float* outp = (float*)d_out;
    int n = in_sizes[0] / NNODE_DIN;  // 50000

    unsigned short* xf = (unsigned short*)d_ws;            // n x 128 fp16
    unsigned short* wth = xf + (size_t)n * NNODE_DOUT;     // 2048 frags x 16B
    unsigned short* wtl = wth + 2048 * 8;

    hipLaunchKernelGGL(k0_wprep, dim3(8), dim3(256), 0, stream, weight, wth, wtl);
    int grid1 = (n + 15) / 16;
    hipLaunchKernelGGL(k1_mfma, dim3(grid1), dim3(64), 0, stream, feat, wth, wtl, xf, n);
    hipLaunchKernelGGL(k2_conv, dim3(n), dim3(128), 0, stream, ew, nbr, bias, xf, outp, n);
}